// Round 18
// baseline (3874.949 us; speedup 1.0000x reference)
//
#include <hip/hip_runtime.h>

typedef __bf16 bf16_t;
typedef __bf16 bf16x4 __attribute__((ext_vector_type(4)));
typedef __bf16 bf16x8 __attribute__((ext_vector_type(8)));
typedef float  f32x4  __attribute__((ext_vector_type(4)));

#define CT 16      // timesteps per chunk (fit: total = NL*CT*2.76us, NL = 1024/CT+11)
#define NCHUNK 64  // chunks (1024 / CT)
#define NLAUNCH 75 // max G = 63 + 2*5 + 1 = 74

__device__ __forceinline__ float sigm_f(float x) {
  float e = __builtin_amdgcn_exp2f(x * -1.44269504f);
  return __builtin_amdgcn_rcpf(1.0f + e);
}
__device__ __forceinline__ float tanh_f(float x) {
  x = fminf(fmaxf(x, -15.0f), 15.0f);
  float e = __builtin_amdgcn_exp2f(x * -2.88539008f);
  float r = __builtin_amdgcn_rcpf(1.0f + e);
  return fmaf(-2.0f * e, r, 1.0f);
}
__device__ __forceinline__ float bf2f(unsigned u16) {
  union { unsigned u; float f; } v; v.u = u16 << 16; return v.f;
}

// ---------------------------------------------------------------- casts
__global__ void cast_f32_to_bf16(const float* __restrict__ src,
                                 bf16_t* __restrict__ dst, long n8) {
  long i = (long)blockIdx.x * blockDim.x + threadIdx.x;
  long stride = (long)gridDim.x * blockDim.x;
  for (; i < n8; i += stride) {
    const float4* sp = (const float4*)src + 2 * i;
    float4 a = sp[0], b = sp[1];
    bf16x8 v;
    v[0] = (bf16_t)a.x; v[1] = (bf16_t)a.y; v[2] = (bf16_t)a.z; v[3] = (bf16_t)a.w;
    v[4] = (bf16_t)b.x; v[5] = (bf16_t)b.y; v[6] = (bf16_t)b.z; v[7] = (bf16_t)b.w;
    ((bf16x8*)dst)[i] = v;
  }
}

// 4x4 bf16 transpose among the 4 lanes of a quad; values packed 2-per-u32.
__device__ __forceinline__ void quad_transpose(unsigned& A, unsigned& B, int q) {
  unsigned tA = __shfl_xor(A, 1);
  unsigned tB = __shfl_xor(B, 1);
  unsigned Ae = (A & 0xFFFFu) | (tA << 16);
  unsigned Ao = (tA >> 16) | (A & 0xFFFF0000u);
  unsigned Be = (B & 0xFFFFu) | (tB << 16);
  unsigned Bo = (tB >> 16) | (B & 0xFFFF0000u);
  unsigned A1 = (q & 1) ? Ao : Ae;
  unsigned B1 = (q & 1) ? Bo : Be;
  unsigned tA1 = __shfl_xor(A1, 2);
  unsigned tB1 = __shfl_xor(B1, 2);
  A = (q & 2) ? tB1 : A1;
  B = (q & 2) ? B1 : tA1;
}

// ---------------------------------------------------------------- wavefront
// grid = 256 x 512 threads. bid<96: SCAN (l=bid>>4, s=bid&15, c=G-2l-1),
// wave w owns j in [32w,32w+32). bid>=96: GEMM (xg for chunk c=G-2l),
// 128M x 256N tiles, jobs stride 160. Within a launch the two roles touch
// opposite ring parities (no race); all true deps cross launch boundaries.
// Scan per-step floor ~2.76us = L2-return BW on the 384KB/step Whh remat
// stream (allocator caps at 128 regs @512thr; residency unreachable -- see
// r2-r16 history). CT=16 minimizes total = NLAUNCH*CT*step since per-gen
// overhead measured ~0 (r9/r10 fit).
__global__ void __launch_bounds__(512)
__attribute__((amdgpu_waves_per_eu(2, 2)))
wavefront(
    const bf16_t* __restrict__ x_bf,   // [1024][256][128]
    const bf16_t* __restrict__ wih0b,  // [768][128]
    const bf16_t* __restrict__ wihb,   // [5][768][256]
    const bf16_t* __restrict__ whhb,   // [6][768][256]
    const float* __restrict__ bih,     // [6][768]
    const float* __restrict__ bhh,     // [6][768]
    const float* __restrict__ h0,      // [6][256][256]
    bf16_t* __restrict__ xgring,       // [6][2][16][CT][768][16]
    bf16_t* __restrict__ hring,        // [5][2][CT][256][256]
    float* __restrict__ hstate,        // [96][16][256]
    float* __restrict__ out_f,         // [1024][256][256]
    int G) {
  extern __shared__ __align__(16) char lds_raw[];
  const int bid = blockIdx.x;
  const int tid = threadIdx.x;
  const int w = tid >> 6, ln = tid & 63;
  const int lq = ln >> 4, lr = ln & 15;

  if (bid < 96) {
    // ================= SCAN =================
    const int l = bid >> 4, s = bid & 15;
    const int c = G - 2 * l - 1;
    if (c < 0 || c >= NCHUNK) return;
    bf16_t* hs = (bf16_t*)lds_raw;      // [2][16][256] swizzled (16 KB)
    char* xl = lds_raw + 16384;         // xg stage [2][24576]
    const int jb = w * 32 + lr;         // j for p=0; p=1 adds 16

    // Whh fragments (192 regs/lane). wf[g][p][kt]; row = g*256+w*32+p*16+lr.
    bf16x8 wf[3][2][8];
#pragma unroll
    for (int g = 0; g < 3; ++g)
#pragma unroll
      for (int p = 0; p < 2; ++p) {
        const size_t gr = (size_t)l * 196608
            + (size_t)(g * 256 + w * 32 + p * 16 + lr) * 256;
#pragma unroll
        for (int kt = 0; kt < 8; ++kt)
          wf[g][p][kt] = *(const bf16x8*)(whhb + gr + kt * 32 + lq * 8);
      }
    const float bhn0 = bhh[l * 768 + 512 + jb];
    const float bhn1 = bhh[l * 768 + 512 + jb + 16];

    float h[2][4];
#pragma unroll
    for (int p = 0; p < 2; ++p)
#pragma unroll
      for (int r = 0; r < 4; ++r) {
        const int bl = lq * 4 + r;
        const int j = jb + p * 16;
        float v;
        if (c == 0) v = h0[(size_t)l * 65536 + (size_t)(s * 16 + bl) * 256 + j];
        else        v = hstate[(size_t)(l * 16 + s) * 4096 + bl * 256 + j];
        h[p][r] = v;
        hs[bl * 256 + ((((j >> 3) ^ (bl & 7)) << 3) | (j & 7))] = (bf16_t)v;
      }

    const char* xgc = (const char*)(xgring
        + ((size_t)((l * 2 + (c & 1)) * 16 + s)) * 196608);
    {  // stage t=0 into xl[0]: per-lane dest == wave base + lane*16 (linear)
#pragma unroll
      for (int u = 0; u < 3; ++u)
        __builtin_amdgcn_global_load_lds(
            (const __attribute__((address_space(1))) void*)(xgc + u * 8192 + tid * 16),
            (__attribute__((address_space(3))) void*)(xl + u * 8192 + tid * 16),
            16, 0, 0);
    }

    const int q = lr & 3;
    const int bq = lq * 4 + q;
    const int jj0 = w * 32 + (lr & 12), jj1 = w * 32 + 16 + (lr & 12);
    const int hswz0 = bq * 512 + ((((jj0 >> 3) ^ (bq & 7)) << 4) | ((jj0 & 7) * 2));
    const int hswz1 = bq * 512 + ((((jj1 >> 3) ^ (bq & 7)) << 4) | ((jj1 & 7) * 2));
    const int xoff = jb * 32 + lq * 8;  // byte offset of (j-row, 4-batch) in xl

    // Incremental output byte pointer (unified l<5 / l==5), stride per t.
    char* pb;
    size_t pstride;
    if (l < 5) {
      pb = (char*)(hring + (size_t)l * 2097152 + (size_t)(c & 1) * 1048576)
           + ((size_t)(s * 16 + bq) * 256 + jj0) * 2;
      pstride = 131072;
    } else {
      pb = (char*)(out_f + (size_t)c * CT * 65536)
           + ((size_t)(s * 16 + bq) * 256 + jj0) * 4;
      pstride = 262144;
    }
    const char* xsrc = xgc + 24576;  // t+1 chunk source (incremental)

    __syncthreads();  // hs init + stage(0) complete
    int rb = 0;
    for (int t = 0; t < CT; ++t) {
      if (t + 1 < CT) {  // stage t+1 into xl[(t+1)&1]
        char* dst = xl + ((t + 1) & 1) * 24576;
#pragma unroll
        for (int u = 0; u < 3; ++u)
          __builtin_amdgcn_global_load_lds(
              (const __attribute__((address_space(1))) void*)(xsrc + u * 8192 + tid * 16),
              (__attribute__((address_space(3))) void*)(dst + u * 8192 + tid * 16),
              16, 0, 0);
        xsrc += 24576;
      }
      f32x4 a00 = {0.f,0.f,0.f,0.f}, a01 = {0.f,0.f,0.f,0.f};
      f32x4 a10 = {0.f,0.f,0.f,0.f}, a11 = {0.f,0.f,0.f,0.f};
      f32x4 a20 = {0.f,0.f,0.f,0.f}, a21 = {0.f,0.f,0.f,0.f};
      const bf16_t* hb = hs + rb * 4096;
#pragma unroll
      for (int kt = 0; kt < 8; ++kt) {
        const bf16x8 acur =
            *(const bf16x8*)&hb[lr * 256 + (((kt * 4 + lq) ^ (lr & 7)) << 3)];
        a00 = __builtin_amdgcn_mfma_f32_16x16x32_bf16(acur, wf[0][0][kt], a00, 0, 0, 0);
        a01 = __builtin_amdgcn_mfma_f32_16x16x32_bf16(acur, wf[0][1][kt], a01, 0, 0, 0);
        a10 = __builtin_amdgcn_mfma_f32_16x16x32_bf16(acur, wf[1][0][kt], a10, 0, 0, 0);
        a11 = __builtin_amdgcn_mfma_f32_16x16x32_bf16(acur, wf[1][1][kt], a11, 0, 0, 0);
        a20 = __builtin_amdgcn_mfma_f32_16x16x32_bf16(acur, wf[2][0][kt], a20, 0, 0, 0);
        a21 = __builtin_amdgcn_mfma_f32_16x16x32_bf16(acur, wf[2][1][kt], a21, 0, 0, 0);
      }
      const char* xb = xl + (t & 1) * 24576 + xoff;
      // p = 0
      {
        const bf16x4 xv0 = *(const bf16x4*)(xb);
        const bf16x4 xv1 = *(const bf16x4*)(xb + 8192);
        const bf16x4 xv2 = *(const bf16x4*)(xb + 16384);
#pragma unroll
        for (int r = 0; r < 4; ++r) {
          const float rg = sigm_f((float)xv0[r] + a00[r]);
          const float zg = sigm_f((float)xv1[r] + a10[r]);
          const float nn = tanh_f((float)xv2[r] + rg * (a20[r] + bhn0));
          h[0][r] = nn + zg * (h[0][r] - nn);
        }
      }
      // p = 1
      {
        const bf16x4 xv0 = *(const bf16x4*)(xb + 512);
        const bf16x4 xv1 = *(const bf16x4*)(xb + 8704);
        const bf16x4 xv2 = *(const bf16x4*)(xb + 16896);
#pragma unroll
        for (int r = 0; r < 4; ++r) {
          const float rg = sigm_f((float)xv0[r] + a01[r]);
          const float zg = sigm_f((float)xv1[r] + a11[r]);
          const float nn = tanh_f((float)xv2[r] + rg * (a21[r] + bhn1));
          h[1][r] = nn + zg * (h[1][r] - nn);
        }
      }
      unsigned P0, P1, P2, P3;
      asm volatile("v_cvt_pk_bf16_f32 %0, %1, %2" : "=v"(P0) : "v"(h[0][0]), "v"(h[0][1]));
      asm volatile("v_cvt_pk_bf16_f32 %0, %1, %2" : "=v"(P1) : "v"(h[0][2]), "v"(h[0][3]));
      asm volatile("v_cvt_pk_bf16_f32 %0, %1, %2" : "=v"(P2) : "v"(h[1][0]), "v"(h[1][1]));
      asm volatile("v_cvt_pk_bf16_f32 %0, %1, %2" : "=v"(P3) : "v"(h[1][2]), "v"(h[1][3]));
      quad_transpose(P0, P1, q);
      quad_transpose(P2, P3, q);
      char* hw = (char*)(hs + (1 - rb) * 4096);
      uint2 pk0; pk0.x = P0; pk0.y = P1;
      uint2 pk1; pk1.x = P2; pk1.y = P3;
      *(uint2*)(hw + hswz0) = pk0;
      *(uint2*)(hw + hswz1) = pk1;
      if (l < 5) {
        *(uint2*)pb = pk0;
        *(uint2*)(pb + 32) = pk1;
      } else {
        float4 o0, o1;
        o0.x = bf2f(P0 & 0xFFFFu); o0.y = bf2f(P0 >> 16);
        o0.z = bf2f(P1 & 0xFFFFu); o0.w = bf2f(P1 >> 16);
        o1.x = bf2f(P2 & 0xFFFFu); o1.y = bf2f(P2 >> 16);
        o1.z = bf2f(P3 & 0xFFFFu); o1.w = bf2f(P3 >> 16);
        *(float4*)pb = o0;
        *(float4*)(pb + 64) = o1;
      }
      pb += pstride;
      __syncthreads();  // drains stage vmcnt + publishes hs(t)
      rb ^= 1;
    }
#pragma unroll
    for (int p = 0; p < 2; ++p)
#pragma unroll
      for (int r = 0; r < 4; ++r)
        hstate[(size_t)(l * 16 + s) * 4096 + (lq * 4 + r) * 256 + jb + p * 16] =
            h[p][r];
  } else {
    // ================= GEMM (xg for chunk c = G - 2l) =================
    // CT=16: per (l,c): 16 s x 2 mt x 3 nt = 96 jobs; 576 total.
    bf16_t* As = (bf16_t*)lds_raw;            // [128][64]
    bf16_t* Bs = (bf16_t*)(lds_raw + 16384);  // [256][64]
    const int wm = w >> 2, wn = w & 3;        // 2 x 4 waves
    for (int job = bid - 96; job < 576; job += 160) {
      const int l = job / 96;
      const int c = G - 2 * l;
      if (c < 0 || c >= NCHUNK) continue;
      const int rem = job % 96;
      const int s = rem & 15, mt = (rem >> 4) & 1, nt = rem >> 5;
      const int K = (l == 0) ? 128 : 256;
      const bf16_t* Ab = (l == 0)
          ? x_bf + (size_t)c * CT * 32768
          : hring + (size_t)(l - 1) * 2097152 + (size_t)(c & 1) * 1048576;
      const bf16_t* Wb = (l == 0) ? wih0b : wihb + (size_t)(l - 1) * 196608;
      const float* bi_p = bih + l * 768;
      const float* bh_p = bhh + l * 768;
      bf16_t* Cg = xgring + ((size_t)((l * 2 + (c & 1)) * 16 + s)) * 196608;

      f32x4 acc[4][4];
      f32x4 zf = {0.f, 0.f, 0.f, 0.f};
#pragma unroll
      for (int mi = 0; mi < 4; ++mi)
#pragma unroll
        for (int ni = 0; ni < 4; ++ni) acc[mi][ni] = zf;

      const int rbase = tid >> 3;       // 0..63
      const int colb = (tid & 7) * 16;  // staged column-byte (linear dest)
      for (int kb = 0; kb < K; kb += 64) {
#pragma unroll
        for (int pA = 0; pA < 2; ++pA) {  // A tile [128][64]: dest=pA*8192+tid*16
          const int row = pA * 64 + rbase;
          const int cbl = colb ^ ((row & 7) << 4);
          const int R = mt * 128 + row;
          const int tt = R >> 4, b = s * 16 + (R & 15);
          const bf16_t* ga = Ab + ((size_t)tt * 256 + b) * K + kb + (cbl >> 1);
          __builtin_amdgcn_global_load_lds(
              (const __attribute__((address_space(1))) void*)ga,
              (__attribute__((address_space(3))) void*)((char*)As + pA * 8192 + tid * 16),
              16, 0, 0);
        }
#pragma unroll
        for (int pB = 0; pB < 4; ++pB) {  // B tile [256][64]: dest=pB*8192+tid*16
          const int row = pB * 64 + rbase;
          const int cbl = colb ^ ((row & 7) << 4);
          const bf16_t* gb = Wb + (size_t)(nt * 256 + row) * K + kb + (cbl >> 1);
          __builtin_amdgcn_global_load_lds(
              (const __attribute__((address_space(1))) void*)gb,
              (__attribute__((address_space(3))) void*)((char*)Bs + pB * 8192 + tid * 16),
              16, 0, 0);
        }
        __syncthreads();
#pragma unroll
        for (int ks = 0; ks < 2; ++ks) {
          bf16x8 av[4], bv[4];
#pragma unroll
          for (int mi = 0; mi < 4; ++mi) {
            const int row = wm * 64 + mi * 16 + lr;
            const int cb = (ks * 64 + lq * 16) ^ ((row & 7) << 4);
            av[mi] = *(const bf16x8*)((const char*)As + row * 128 + cb);
          }
#pragma unroll
          for (int ni = 0; ni < 4; ++ni) {
            const int row = wn * 64 + ni * 16 + lr;
            const int cb = (ks * 64 + lq * 16) ^ ((row & 7) << 4);
            bv[ni] = *(const bf16x8*)((const char*)Bs + row * 128 + cb);
          }
#pragma unroll
          for (int mi = 0; mi < 4; ++mi)
#pragma unroll
            for (int ni = 0; ni < 4; ++ni)
              acc[mi][ni] = __builtin_amdgcn_mfma_f32_16x16x32_bf16(
                  av[mi], bv[ni], acc[mi][ni], 0, 0, 0);
        }
        __syncthreads();
      }
#pragma unroll
      for (int ni = 0; ni < 4; ++ni) {
        const int g = nt * 256 + wn * 64 + ni * 16 + lr;
        const float bi = bi_p[g] + (g < 512 ? bh_p[g] : 0.0f);
#pragma unroll
        for (int mi = 0; mi < 4; ++mi) {
          const int tt = mt * 8 + wm * 4 + mi;
          bf16x4 v;
#pragma unroll
          for (int r = 0; r < 4; ++r) v[r] = (bf16_t)(acc[mi][ni][r] + bi);
          *(bf16x4*)&Cg[(size_t)tt * 12288 + g * 16 + lq * 4] = v;
        }
      }
    }
  }
}

// ---------------------------------------------------------------- launch
extern "C" void kernel_launch(void* const* d_in, const int* in_sizes, int n_in,
                              void* d_out, int out_size, void* d_ws, size_t ws_size,
                              hipStream_t stream) {
  const float* x    = (const float*)d_in[0];
  const float* h0   = (const float*)d_in[1];
  const float* wih0 = (const float*)d_in[2];
  const float* wih  = (const float*)d_in[3];
  const float* whh  = (const float*)d_in[4];
  const float* bih  = (const float*)d_in[5];
  const float* bhh  = (const float*)d_in[6];

  // ws layout (bytes), CT=16:
  //  xgring [6][2][16][16][768][16] bf16 :  75,497,472
  //  hring  [5][2][16][256][256]    bf16 :  20,971,520
  //  x_bf   [1024][256][128]        bf16 :  67,108,864
  //  whh_bf / wih0_bf / wih_bf / hstate  :   ~6.1 MB
  char* ws = (char*)d_ws;
  bf16_t* xgring  = (bf16_t*)(ws);
  bf16_t* hringp  = (bf16_t*)(ws + 75497472ull);
  bf16_t* x_bf    = (bf16_t*)(ws + 96468992ull);
  bf16_t* whh_bf  = (bf16_t*)(ws + 163577856ull);
  bf16_t* wih0_bf = (bf16_t*)(ws + 165937152ull);
  bf16_t* wih_bf  = (bf16_t*)(ws + 166133760ull);
  float*  hstate  = (float*)(ws + 168099840ull);

  cast_f32_to_bf16<<<2048, 256, 0, stream>>>(x, x_bf, 4194304L);
  cast_f32_to_bf16<<<576, 256, 0, stream>>>(whh, whh_bf, 147456L);
  cast_f32_to_bf16<<<48, 256, 0, stream>>>(wih0, wih0_bf, 12288L);
  cast_f32_to_bf16<<<480, 256, 0, stream>>>(wih, wih_bf, 122880L);

  for (int G = 0; G < NLAUNCH; ++G) {
    wavefront<<<256, 512, 65536, stream>>>(x_bf, wih0_bf, wih_bf, whh_bf,
                                           bih, bhh, h0, xgring, hringp,
                                           hstate, (float*)d_out, G);
  }
}

// Round 19
// 3745.355 us; speedup vs baseline: 1.0346x; 1.0346x over previous
//
#include <hip/hip_runtime.h>

typedef __bf16 bf16_t;
typedef __bf16 bf16x4 __attribute__((ext_vector_type(4)));
typedef __bf16 bf16x8 __attribute__((ext_vector_type(8)));
typedef float  f32x4  __attribute__((ext_vector_type(4)));

#define CT 32      // timesteps per chunk (measured optimum: launch = 16.2us + CT*2.22us,
#define NCHUNK 32  //  total = (1024/CT+11)*launch minimized at CT~26-32; CT=16 and 64 both worse)
#define NLAUNCH 43 // max G = 31 + 2*5 + 1 = 42

__device__ __forceinline__ float sigm_f(float x) {
  float e = __builtin_amdgcn_exp2f(x * -1.44269504f);
  return __builtin_amdgcn_rcpf(1.0f + e);
}
__device__ __forceinline__ float tanh_f(float x) {
  x = fminf(fmaxf(x, -15.0f), 15.0f);
  float e = __builtin_amdgcn_exp2f(x * -2.88539008f);
  float r = __builtin_amdgcn_rcpf(1.0f + e);
  return fmaf(-2.0f * e, r, 1.0f);
}
__device__ __forceinline__ float bf2f(unsigned u16) {
  union { unsigned u; float f; } v; v.u = u16 << 16; return v.f;
}

// ---------------------------------------------------------------- casts
__global__ void cast_f32_to_bf16(const float* __restrict__ src,
                                 bf16_t* __restrict__ dst, long n8) {
  long i = (long)blockIdx.x * blockDim.x + threadIdx.x;
  long stride = (long)gridDim.x * blockDim.x;
  for (; i < n8; i += stride) {
    const float4* sp = (const float4*)src + 2 * i;
    float4 a = sp[0], b = sp[1];
    bf16x8 v;
    v[0] = (bf16_t)a.x; v[1] = (bf16_t)a.y; v[2] = (bf16_t)a.z; v[3] = (bf16_t)a.w;
    v[4] = (bf16_t)b.x; v[5] = (bf16_t)b.y; v[6] = (bf16_t)b.z; v[7] = (bf16_t)b.w;
    ((bf16x8*)dst)[i] = v;
  }
}

// 4x4 bf16 transpose among the 4 lanes of a quad; values packed 2-per-u32.
__device__ __forceinline__ void quad_transpose(unsigned& A, unsigned& B, int q) {
  unsigned tA = __shfl_xor(A, 1);
  unsigned tB = __shfl_xor(B, 1);
  unsigned Ae = (A & 0xFFFFu) | (tA << 16);
  unsigned Ao = (tA >> 16) | (A & 0xFFFF0000u);
  unsigned Be = (B & 0xFFFFu) | (tB << 16);
  unsigned Bo = (tB >> 16) | (B & 0xFFFF0000u);
  unsigned A1 = (q & 1) ? Ao : Ae;
  unsigned B1 = (q & 1) ? Bo : Be;
  unsigned tA1 = __shfl_xor(A1, 2);
  unsigned tB1 = __shfl_xor(B1, 2);
  A = (q & 2) ? tB1 : A1;
  B = (q & 2) ? B1 : tA1;
}

// ---------------------------------------------------------------- wavefront
// grid = 256 x 512 threads. bid<96: SCAN (l=bid>>4, s=bid&15, c=G-2l-1),
// wave w owns j in [32w,32w+32). bid>=96: GEMM (xg for chunk c=G-2l),
// 128M x 256N tiles, jobs stride 160. Within a launch the two roles touch
// opposite ring parities (no race); all true deps cross launch boundaries.
// The scan's Whh set (192 regs/lane) exceeds the allocator's 2-blocks/CU
// budget (128 @512thr; every residency mechanism measured dead or unsound,
// r2-r16) -> remat-streamed from L2 at ~2.2us/step. This kernel is the
// verified floor of that structure: ~3.75 ms end-to-end.
__global__ void __launch_bounds__(512)
__attribute__((amdgpu_waves_per_eu(2, 2)))
wavefront(
    const bf16_t* __restrict__ x_bf,   // [1024][256][128]
    const bf16_t* __restrict__ wih0b,  // [768][128]
    const bf16_t* __restrict__ wihb,   // [5][768][256]
    const bf16_t* __restrict__ whhb,   // [6][768][256]
    const float* __restrict__ bih,     // [6][768]
    const float* __restrict__ bhh,     // [6][768]
    const float* __restrict__ h0,      // [6][256][256]
    bf16_t* __restrict__ xgring,       // [6][2][16][CT][768][16]
    bf16_t* __restrict__ hring,        // [5][2][CT][256][256]
    float* __restrict__ hstate,        // [96][16][256]
    float* __restrict__ out_f,         // [1024][256][256]
    int G) {
  extern __shared__ __align__(16) char lds_raw[];
  const int bid = blockIdx.x;
  const int tid = threadIdx.x;
  const int w = tid >> 6, ln = tid & 63;
  const int lq = ln >> 4, lr = ln & 15;

  if (bid < 96) {
    // ================= SCAN =================
    const int l = bid >> 4, s = bid & 15;
    const int c = G - 2 * l - 1;
    if (c < 0 || c >= NCHUNK) return;
    bf16_t* hs = (bf16_t*)lds_raw;      // [2][16][256] swizzled (16 KB)
    char* xl = lds_raw + 16384;         // xg stage [2][24576]
    const int jb = w * 32 + lr;         // j for p=0; p=1 adds 16

    // Whh fragments (192 regs/lane). wf[g][p][kt]; row = g*256+w*32+p*16+lr.
    bf16x8 wf[3][2][8];
#pragma unroll
    for (int g = 0; g < 3; ++g)
#pragma unroll
      for (int p = 0; p < 2; ++p) {
        const size_t gr = (size_t)l * 196608
            + (size_t)(g * 256 + w * 32 + p * 16 + lr) * 256;
#pragma unroll
        for (int kt = 0; kt < 8; ++kt)
          wf[g][p][kt] = *(const bf16x8*)(whhb + gr + kt * 32 + lq * 8);
      }
    const float bhn0 = bhh[l * 768 + 512 + jb];
    const float bhn1 = bhh[l * 768 + 512 + jb + 16];

    float h[2][4];
#pragma unroll
    for (int p = 0; p < 2; ++p)
#pragma unroll
      for (int r = 0; r < 4; ++r) {
        const int bl = lq * 4 + r;
        const int j = jb + p * 16;
        float v;
        if (c == 0) v = h0[(size_t)l * 65536 + (size_t)(s * 16 + bl) * 256 + j];
        else        v = hstate[(size_t)(l * 16 + s) * 4096 + bl * 256 + j];
        h[p][r] = v;
        hs[bl * 256 + ((((j >> 3) ^ (bl & 7)) << 3) | (j & 7))] = (bf16_t)v;
      }

    const char* xgc = (const char*)(xgring
        + ((size_t)((l * 2 + (c & 1)) * 16 + s)) * 393216);
    {  // stage t=0 into xl[0]: per-lane dest == wave base + lane*16 (linear)
#pragma unroll
      for (int u = 0; u < 3; ++u)
        __builtin_amdgcn_global_load_lds(
            (const __attribute__((address_space(1))) void*)(xgc + u * 8192 + tid * 16),
            (__attribute__((address_space(3))) void*)(xl + u * 8192 + tid * 16),
            16, 0, 0);
    }

    const int q = lr & 3;
    const int bq = lq * 4 + q;
    const int jj0 = w * 32 + (lr & 12), jj1 = w * 32 + 16 + (lr & 12);
    const int hswz0 = bq * 512 + ((((jj0 >> 3) ^ (bq & 7)) << 4) | ((jj0 & 7) * 2));
    const int hswz1 = bq * 512 + ((((jj1 >> 3) ^ (bq & 7)) << 4) | ((jj1 & 7) * 2));
    const int xoff = jb * 32 + lq * 8;  // byte offset of (j-row, 4-batch) in xl

    // Incremental output byte pointer (unified l<5 / l==5), stride per t.
    char* pb;
    size_t pstride;
    if (l < 5) {
      pb = (char*)(hring + (size_t)l * 4194304 + (size_t)(c & 1) * 2097152)
           + ((size_t)(s * 16 + bq) * 256 + jj0) * 2;
      pstride = 131072;
    } else {
      pb = (char*)(out_f + (size_t)c * CT * 65536)
           + ((size_t)(s * 16 + bq) * 256 + jj0) * 4;
      pstride = 262144;
    }
    const char* xsrc = xgc + 24576;  // t+1 chunk source (incremental)

    __syncthreads();  // hs init + stage(0) complete
    int rb = 0;
    for (int t = 0; t < CT; ++t) {
      if (t + 1 < CT) {  // stage t+1 into xl[(t+1)&1]
        char* dst = xl + ((t + 1) & 1) * 24576;
#pragma unroll
        for (int u = 0; u < 3; ++u)
          __builtin_amdgcn_global_load_lds(
              (const __attribute__((address_space(1))) void*)(xsrc + u * 8192 + tid * 16),
              (__attribute__((address_space(3))) void*)(dst + u * 8192 + tid * 16),
              16, 0, 0);
        xsrc += 24576;
      }
      f32x4 a00 = {0.f,0.f,0.f,0.f}, a01 = {0.f,0.f,0.f,0.f};
      f32x4 a10 = {0.f,0.f,0.f,0.f}, a11 = {0.f,0.f,0.f,0.f};
      f32x4 a20 = {0.f,0.f,0.f,0.f}, a21 = {0.f,0.f,0.f,0.f};
      const bf16_t* hb = hs + rb * 4096;
#pragma unroll
      for (int kt = 0; kt < 8; ++kt) {
        const bf16x8 acur =
            *(const bf16x8*)&hb[lr * 256 + (((kt * 4 + lq) ^ (lr & 7)) << 3)];
        a00 = __builtin_amdgcn_mfma_f32_16x16x32_bf16(acur, wf[0][0][kt], a00, 0, 0, 0);
        a01 = __builtin_amdgcn_mfma_f32_16x16x32_bf16(acur, wf[0][1][kt], a01, 0, 0, 0);
        a10 = __builtin_amdgcn_mfma_f32_16x16x32_bf16(acur, wf[1][0][kt], a10, 0, 0, 0);
        a11 = __builtin_amdgcn_mfma_f32_16x16x32_bf16(acur, wf[1][1][kt], a11, 0, 0, 0);
        a20 = __builtin_amdgcn_mfma_f32_16x16x32_bf16(acur, wf[2][0][kt], a20, 0, 0, 0);
        a21 = __builtin_amdgcn_mfma_f32_16x16x32_bf16(acur, wf[2][1][kt], a21, 0, 0, 0);
      }
      const char* xb = xl + (t & 1) * 24576 + xoff;
      // p = 0
      {
        const bf16x4 xv0 = *(const bf16x4*)(xb);
        const bf16x4 xv1 = *(const bf16x4*)(xb + 8192);
        const bf16x4 xv2 = *(const bf16x4*)(xb + 16384);
#pragma unroll
        for (int r = 0; r < 4; ++r) {
          const float rg = sigm_f((float)xv0[r] + a00[r]);
          const float zg = sigm_f((float)xv1[r] + a10[r]);
          const float nn = tanh_f((float)xv2[r] + rg * (a20[r] + bhn0));
          h[0][r] = nn + zg * (h[0][r] - nn);
        }
      }
      // p = 1
      {
        const bf16x4 xv0 = *(const bf16x4*)(xb + 512);
        const bf16x4 xv1 = *(const bf16x4*)(xb + 8704);
        const bf16x4 xv2 = *(const bf16x4*)(xb + 16896);
#pragma unroll
        for (int r = 0; r < 4; ++r) {
          const float rg = sigm_f((float)xv0[r] + a01[r]);
          const float zg = sigm_f((float)xv1[r] + a11[r]);
          const float nn = tanh_f((float)xv2[r] + rg * (a21[r] + bhn1));
          h[1][r] = nn + zg * (h[1][r] - nn);
        }
      }
      unsigned P0, P1, P2, P3;
      asm volatile("v_cvt_pk_bf16_f32 %0, %1, %2" : "=v"(P0) : "v"(h[0][0]), "v"(h[0][1]));
      asm volatile("v_cvt_pk_bf16_f32 %0, %1, %2" : "=v"(P1) : "v"(h[0][2]), "v"(h[0][3]));
      asm volatile("v_cvt_pk_bf16_f32 %0, %1, %2" : "=v"(P2) : "v"(h[1][0]), "v"(h[1][1]));
      asm volatile("v_cvt_pk_bf16_f32 %0, %1, %2" : "=v"(P3) : "v"(h[1][2]), "v"(h[1][3]));
      quad_transpose(P0, P1, q);
      quad_transpose(P2, P3, q);
      char* hw = (char*)(hs + (1 - rb) * 4096);
      uint2 pk0; pk0.x = P0; pk0.y = P1;
      uint2 pk1; pk1.x = P2; pk1.y = P3;
      *(uint2*)(hw + hswz0) = pk0;
      *(uint2*)(hw + hswz1) = pk1;
      if (l < 5) {
        *(uint2*)pb = pk0;
        *(uint2*)(pb + 32) = pk1;
      } else {
        float4 o0, o1;
        o0.x = bf2f(P0 & 0xFFFFu); o0.y = bf2f(P0 >> 16);
        o0.z = bf2f(P1 & 0xFFFFu); o0.w = bf2f(P1 >> 16);
        o1.x = bf2f(P2 & 0xFFFFu); o1.y = bf2f(P2 >> 16);
        o1.z = bf2f(P3 & 0xFFFFu); o1.w = bf2f(P3 >> 16);
        *(float4*)pb = o0;
        *(float4*)(pb + 64) = o1;
      }
      pb += pstride;
      __syncthreads();  // drains stage vmcnt + publishes hs(t)
      rb ^= 1;
    }
#pragma unroll
    for (int p = 0; p < 2; ++p)
#pragma unroll
      for (int r = 0; r < 4; ++r)
        hstate[(size_t)(l * 16 + s) * 4096 + (lq * 4 + r) * 256 + jb + p * 16] =
            h[p][r];
  } else {
    // ================= GEMM (xg for chunk c = G - 2l) =================
    bf16_t* As = (bf16_t*)lds_raw;            // [128][64]
    bf16_t* Bs = (bf16_t*)(lds_raw + 16384);  // [256][64]
    const int wm = w >> 2, wn = w & 3;        // 2 x 4 waves
    for (int job = bid - 96; job < 1152; job += 160) {
      const int l = job / 192;
      const int c = G - 2 * l;
      if (c < 0 || c >= NCHUNK) continue;
      const int rem = job % 192;
      const int s = rem & 15, mt = (rem >> 4) & 3, nt = rem >> 6;
      const int K = (l == 0) ? 128 : 256;
      const bf16_t* Ab = (l == 0)
          ? x_bf + (size_t)c * CT * 32768
          : hring + (size_t)(l - 1) * 4194304 + (size_t)(c & 1) * 2097152;
      const bf16_t* Wb = (l == 0) ? wih0b : wihb + (size_t)(l - 1) * 196608;
      const float* bi_p = bih + l * 768;
      const float* bh_p = bhh + l * 768;
      bf16_t* Cg = xgring + ((size_t)((l * 2 + (c & 1)) * 16 + s)) * 393216;

      f32x4 acc[4][4];
      f32x4 zf = {0.f, 0.f, 0.f, 0.f};
#pragma unroll
      for (int mi = 0; mi < 4; ++mi)
#pragma unroll
        for (int ni = 0; ni < 4; ++ni) acc[mi][ni] = zf;

      const int rbase = tid >> 3;       // 0..63
      const int colb = (tid & 7) * 16;  // staged column-byte (linear dest)
      for (int kb = 0; kb < K; kb += 64) {
#pragma unroll
        for (int pA = 0; pA < 2; ++pA) {  // A tile [128][64]: dest=pA*8192+tid*16
          const int row = pA * 64 + rbase;
          const int cbl = colb ^ ((row & 7) << 4);
          const int R = mt * 128 + row;
          const int tt = R >> 4, b = s * 16 + (R & 15);
          const bf16_t* ga = Ab + ((size_t)tt * 256 + b) * K + kb + (cbl >> 1);
          __builtin_amdgcn_global_load_lds(
              (const __attribute__((address_space(1))) void*)ga,
              (__attribute__((address_space(3))) void*)((char*)As + pA * 8192 + tid * 16),
              16, 0, 0);
        }
#pragma unroll
        for (int pB = 0; pB < 4; ++pB) {  // B tile [256][64]: dest=pB*8192+tid*16
          const int row = pB * 64 + rbase;
          const int cbl = colb ^ ((row & 7) << 4);
          const bf16_t* gb = Wb + (size_t)(nt * 256 + row) * K + kb + (cbl >> 1);
          __builtin_amdgcn_global_load_lds(
              (const __attribute__((address_space(1))) void*)gb,
              (__attribute__((address_space(3))) void*)((char*)Bs + pB * 8192 + tid * 16),
              16, 0, 0);
        }
        __syncthreads();
#pragma unroll
        for (int ks = 0; ks < 2; ++ks) {
          bf16x8 av[4], bv[4];
#pragma unroll
          for (int mi = 0; mi < 4; ++mi) {
            const int row = wm * 64 + mi * 16 + lr;
            const int cb = (ks * 64 + lq * 16) ^ ((row & 7) << 4);
            av[mi] = *(const bf16x8*)((const char*)As + row * 128 + cb);
          }
#pragma unroll
          for (int ni = 0; ni < 4; ++ni) {
            const int row = wn * 64 + ni * 16 + lr;
            const int cb = (ks * 64 + lq * 16) ^ ((row & 7) << 4);
            bv[ni] = *(const bf16x8*)((const char*)Bs + row * 128 + cb);
          }
#pragma unroll
          for (int mi = 0; mi < 4; ++mi)
#pragma unroll
            for (int ni = 0; ni < 4; ++ni)
              acc[mi][ni] = __builtin_amdgcn_mfma_f32_16x16x32_bf16(
                  av[mi], bv[ni], acc[mi][ni], 0, 0, 0);
        }
        __syncthreads();
      }
#pragma unroll
      for (int ni = 0; ni < 4; ++ni) {
        const int g = nt * 256 + wn * 64 + ni * 16 + lr;
        const float bi = bi_p[g] + (g < 512 ? bh_p[g] : 0.0f);
#pragma unroll
        for (int mi = 0; mi < 4; ++mi) {
          const int tt = mt * 8 + wm * 4 + mi;
          bf16x4 v;
#pragma unroll
          for (int r = 0; r < 4; ++r) v[r] = (bf16_t)(acc[mi][ni][r] + bi);
          *(bf16x4*)&Cg[(size_t)tt * 12288 + g * 16 + lq * 4] = v;
        }
      }
    }
  }
}

// ---------------------------------------------------------------- launch
extern "C" void kernel_launch(void* const* d_in, const int* in_sizes, int n_in,
                              void* d_out, int out_size, void* d_ws, size_t ws_size,
                              hipStream_t stream) {
  const float* x    = (const float*)d_in[0];
  const float* h0   = (const float*)d_in[1];
  const float* wih0 = (const float*)d_in[2];
  const float* wih  = (const float*)d_in[3];
  const float* whh  = (const float*)d_in[4];
  const float* bih  = (const float*)d_in[5];
  const float* bhh  = (const float*)d_in[6];

  char* ws = (char*)d_ws;
  bf16_t* xgring  = (bf16_t*)(ws);
  bf16_t* hringp  = (bf16_t*)(ws + 150994944ull);
  bf16_t* x_bf    = (bf16_t*)(ws + 192937984ull);
  bf16_t* whh_bf  = (bf16_t*)(ws + 260046848ull);
  bf16_t* wih0_bf = (bf16_t*)(ws + 262406144ull);
  bf16_t* wih_bf  = (bf16_t*)(ws + 262602752ull);
  float*  hstate  = (float*)(ws + 264568832ull);

  cast_f32_to_bf16<<<2048, 256, 0, stream>>>(x, x_bf, 4194304L);
  cast_f32_to_bf16<<<576, 256, 0, stream>>>(whh, whh_bf, 147456L);
  cast_f32_to_bf16<<<48, 256, 0, stream>>>(wih0, wih0_bf, 12288L);
  cast_f32_to_bf16<<<480, 256, 0, stream>>>(wih, wih_bf, 122880L);

  for (int G = 0; G < NLAUNCH; ++G) {
    wavefront<<<256, 512, 65536, stream>>>(x_bf, wih0_bf, wih_bf, whh_bf,
                                           bih, bhh, h0, xgring, hringp,
                                           hstate, (float*)d_out, G);
  }
}